// Round 2
// baseline (93.495 us; speedup 1.0000x reference)
//
#include <hip/hip_runtime.h>

// GAT forward, O(N*HD) via bucket-partition decomposition. B=8,N=1024,F=128,H=4,HD=32.
// score(i,j)=s_i+d_j; negative iff d_j < -s_i. Per (b,h), partition j into 1024
// equi-width buckets by d (monotone f(d)); for row i with kb=f(-s_i):
//   out[i,:] = (c2*(PB[q0]+bnd_lo) + c1*(Suf[q1]+bnd_hi)) / (same on scalars)
// q0/q1 = bucket kb start/end; boundary bucket resolved by exact d_j < -s_i compares.
// PB: exclusive prefix of e^{0.2d}*h in bucket order; Suf: inclusive suffix of e^d*h.
//
// R2: proj retiled 8-row blocks (1024 blk = 4/CU, 4 waves/SIMD; 160 LDS reads /
//     512 FMA per thread, was 288/1024 at 2 waves/SIMD). Bitonic sort (55 dependent
//     network steps) replaced by counting sort into 1024 buckets (2 barriers);
//     out_kernel: binary search -> direct bucket index + exact boundary loop
//     (avg ~2.6 elems). scan_kernel unchanged (order-agnostic).
// bh = blockIdx&31 keeps each bh's blocks on one XCD (round-robin %8) for L2 locality.

constexpr int CB  = 8;
constexpr int CN  = 1024;
constexpr int CF  = 128;
constexpr int CH  = 4;
constexpr int CHD = 32;
constexpr int CBH = CB * CH;        // 32
constexpr int CROWS = CB * CN;      // 8192
constexpr int TROWS = CN + 1;       // 1025 table rows (row 1024 = zeros)
constexpr int NBK = 1024;           // buckets per bh

// ---------------- K1: projection + exact s/d ----------------
// 1024 blocks x 256 thr; block = 8 rows x 128 cols; thread = (r=tid>>5, c4=tid&31)
// owning 4 cols. 4 blocks/CU (LDS 36.3 KB) -> 16 waves/CU. x reads broadcast;
// W reads 512B/wave-instr. s/d: partial dot of acc[4], reduced over the 8
// c4-threads of (row,head) via shfl_xor 1/2/4 (exact).
__global__ __launch_bounds__(256) void proj_kernel(
    const float* __restrict__ x, const float* __restrict__ W,
    const float* __restrict__ a_src, const float* __restrict__ a_dst,
    float* __restrict__ h_ws, float* __restrict__ sarr, float* __restrict__ darr)
{
    __shared__ float xs[8 * 132];       // 4.2 KB, padded stride
    __shared__ float wslab[64 * 128];   // 32 KB

    const int tid = threadIdx.x, row0 = blockIdx.x * 8;

    // stage x tile: 256 float4, coalesced; one per thread
    {
        const int rr = tid >> 5, k4 = tid & 31;
        *(float4*)(xs + rr * 132 + k4 * 4) = ((const float4*)x)[(size_t)row0 * 32 + tid];
    }

    const int r = tid >> 5, c4 = tid & 31;        // row, col-group of 4
    const int head = c4 >> 3, dd0 = (c4 & 7) * 4;
    float acc[4] = {0.f, 0.f, 0.f, 0.f};

    const float4* W4 = (const float4*)W;
    for (int slab = 0; slab < 2; ++slab) {
        __syncthreads();                           // xs ready; wslab free to overwrite
        #pragma unroll
        for (int m = 0; m < 8; ++m) {
            const int idx = m * 256 + tid;         // 0..2047
            const int kk = idx >> 5, k4 = idx & 31;
            *(float4*)(wslab + kk * 128 + k4 * 4) = W4[(size_t)(slab * 64 + kk) * 32 + k4];
        }
        __syncthreads();
        #pragma unroll 4
        for (int k4 = 0; k4 < 16; ++k4) {
            const float4 xv = *(const float4*)(xs + r * 132 + slab * 64 + k4 * 4);
            const float xq[4] = {xv.x, xv.y, xv.z, xv.w};
            #pragma unroll
            for (int q = 0; q < 4; ++q) {
                const int kk = k4 * 4 + q;
                const float4 wv = *(const float4*)(wslab + kk * 128 + c4 * 4);
                const float xk = xq[q];
                acc[0] += xk * wv.x; acc[1] += xk * wv.y;
                acc[2] += xk * wv.z; acc[3] += xk * wv.w;
            }
        }
    }

    const float4 as = *(const float4*)(a_src + head * CHD + dd0);
    const float4 ad = *(const float4*)(a_dst + head * CHD + dd0);
    float sp = acc[0]*as.x + acc[1]*as.y + acc[2]*as.z + acc[3]*as.w;
    float dp = acc[0]*ad.x + acc[1]*ad.y + acc[2]*ad.z + acc[3]*ad.w;
    // the 8 threads of (row,head) are consecutive lanes (bits 0..2 of lane)
    sp += __shfl_xor(sp, 1); sp += __shfl_xor(sp, 2); sp += __shfl_xor(sp, 4);
    dp += __shfl_xor(dp, 1); dp += __shfl_xor(dp, 2); dp += __shfl_xor(dp, 4);

    const int rowg = row0 + r, b = rowg >> 10, n = rowg & 1023;
    const int bh = b * CH + head;
    *(float4*)(h_ws + (size_t)(bh * CN + n) * CHD + dd0) =
        make_float4(acc[0], acc[1], acc[2], acc[3]);
    if ((c4 & 7) == 0) {
        sarr[bh * CN + n] = sp;
        darr[bh * CN + n] = dp;
    }
}

// ---------------- K2: counting sort into 1024 equi-width buckets ----------
// 32 blocks x 1024 thr. f(d) = clamp((d-dmin)*1024/range, 0, 1023) — monotone,
// identical formula used in out_kernel for thr. Within-bucket order arbitrary
// (only bucket-boundary table rows are consumed downstream).
__global__ __launch_bounds__(1024) void count_kernel(
    const float* __restrict__ darr, float* __restrict__ dsrt_g,
    int* __restrict__ pj_g, int* __restrict__ bs_g, float* __restrict__ prm_g,
    float* __restrict__ sPB_g, float* __restrict__ sSF_g, float* __restrict__ tbl_g)
{
    __shared__ int   cnts[NBK];
    __shared__ int   startsS[NBK];
    __shared__ float redS[32];          // [0..15] wave mins, [16..31] wave maxs
    __shared__ int   wsumS[16];
    __shared__ float prmS[2];

    const int bh = blockIdx.x, tid = threadIdx.x;
    const int lane = tid & 63, wid = tid >> 6;

    const float d = darr[bh * CN + tid];

    // block min/max: wave shuffle reduce + tiny LDS reduce
    float mn = d, mx = d;
    #pragma unroll
    for (int off = 1; off < 64; off <<= 1) {
        mn = fminf(mn, __shfl_xor(mn, off));
        mx = fmaxf(mx, __shfl_xor(mx, off));
    }
    if (lane == 0) { redS[wid] = mn; redS[16 + wid] = mx; }
    cnts[tid] = 0;
    __syncthreads();
    if (tid == 0) {
        float m0 = redS[0], m1 = redS[16];
        for (int w = 1; w < 16; ++w) { m0 = fminf(m0, redS[w]); m1 = fmaxf(m1, redS[16 + w]); }
        const float rng = fmaxf(m1 - m0, 1e-30f);
        const float invw = (float)NBK / rng;
        prmS[0] = m0; prmS[1] = invw;
        prm_g[bh * 2] = m0; prm_g[bh * 2 + 1] = invw;
    }
    __syncthreads();
    const float mnb = prmS[0], invw = prmS[1];
    const int f = (int)fminf(fmaxf((d - mnb) * invw, 0.0f), 1023.0f);
    const int rank = atomicAdd(&cnts[f], 1);
    __syncthreads();

    // exclusive scan of 1024 counts: in-wave shfl scan + 16-wave combine
    const int c = cnts[tid];
    int incl = c;
    #pragma unroll
    for (int off = 1; off < 64; off <<= 1) {
        const int t = __shfl_up(incl, off);
        if (lane >= off) incl += t;
    }
    if (lane == 63) wsumS[wid] = incl;
    __syncthreads();
    if (tid < 16) {
        const int v = wsumS[tid];
        int iv = v;
        #pragma unroll
        for (int off = 1; off < 16; off <<= 1) {
            const int t = __shfl_up(iv, off);
            if (tid >= off) iv += t;
        }
        wsumS[tid] = iv - v;            // exclusive wave offset
    }
    __syncthreads();
    const int excl = incl - c + wsumS[wid];   // exclusive start of bucket tid
    startsS[tid] = excl;
    bs_g[bh * (NBK + 1) + tid] = excl;
    __syncthreads();

    const int pos = startsS[f] + rank;
    dsrt_g[bh * CN + pos] = d;
    pj_g[bh * CN + pos]   = tid;

    if (tid == 0) {
        bs_g[bh * (NBK + 1) + NBK] = CN;
        sPB_g[bh * TROWS + CN] = 0.f;
        sSF_g[bh * TROWS + CN] = 0.f;
    }
    if (tid < 64) tbl_g[(size_t)bh * TROWS * 64 + (size_t)CN * 64 + tid] = 0.f;
}

// ---------------- K3: chunk-local scans (unchanged; order-agnostic) --------
// 256 blocks x 256 thr: block = (bh = idx&31, cg = idx>>5) covering chunks
// cg*4..cg*4+3. Thread = (dir=tid>>7, cidx=(tid>>5)&3, dd=tid&31).
__global__ __launch_bounds__(256) void scan_kernel(
    const float* __restrict__ h_ws, const float* __restrict__ dsrt_g,
    const int* __restrict__ pj_g, float* __restrict__ tbl_g,
    float* __restrict__ sPB_g, float* __restrict__ sSF_g,
    float* __restrict__ ctF_g, float* __restrict__ ctB_g,
    float* __restrict__ ctSF_g, float* __restrict__ ctSB_g)
{
    __shared__ float dch[128];
    __shared__ int   pch[128];
    const int bh = blockIdx.x & 31, cg = blockIdx.x >> 5;
    const int tid = threadIdx.x, base = cg * 128;

    if (tid < 128) dch[tid] = dsrt_g[bh * CN + base + tid];
    else           pch[tid - 128] = pj_g[bh * CN + base + (tid - 128)];
    __syncthreads();

    const int dir = tid >> 7, cidx = (tid >> 5) & 3, dd = tid & 31;
    const int c = cg * 4 + cidx, lb = cidx * 32;
    const float* hb = h_ws + (size_t)bh * CN * CHD;
    float* tbl = tbl_g + (size_t)bh * TROWS * 64;

    if (dir == 0) {   // forward: exclusive prefix of e^{0.2d}*h
        float accF = 0.f, accS = 0.f;
        for (int bt = 0; bt < 2; ++bt) {
            float hv[16], dv[16];
            #pragma unroll
            for (int t = 0; t < 16; ++t) {
                const int lp = lb + bt * 16 + t;
                hv[t] = hb[(size_t)pch[lp] * CHD + dd];
                dv[t] = dch[lp];
            }
            #pragma unroll
            for (int t = 0; t < 16; ++t) {
                const int pos = base + lb + bt * 16 + t;
                const float cf = __expf(0.2f * dv[t]);
                tbl[pos * 64 + dd] = accF;
                if (dd == 0) sPB_g[bh * TROWS + pos] = accS;
                accF += cf * hv[t];
                accS += cf;
            }
        }
        ctF_g[(bh * 32 + c) * 32 + dd] = accF;
        if (dd == 0) ctSF_g[bh * 32 + c] = accS;
    } else {          // backward: inclusive suffix of e^{d}*h
        float accB = 0.f, accS = 0.f;
        for (int bt = 0; bt < 2; ++bt) {
            float hv[16], dv[16];
            #pragma unroll
            for (int t = 0; t < 16; ++t) {
                const int lp = lb + 31 - (bt * 16 + t);
                hv[t] = hb[(size_t)pch[lp] * CHD + dd];
                dv[t] = dch[lp];
            }
            #pragma unroll
            for (int t = 0; t < 16; ++t) {
                const int pos = base + lb + 31 - (bt * 16 + t);
                const float cf = __expf(dv[t]);
                accB += cf * hv[t];
                accS += cf;
                tbl[pos * 64 + 32 + dd] = accB;
                if (dd == 0) sSF_g[bh * TROWS + pos] = accS;
            }
        }
        ctB_g[(bh * 32 + c) * 32 + dd] = accB;
        if (dd == 0) ctSB_g[bh * 32 + c] = accS;
    }
}

// ---------------- K4: bucket lookup + boundary resolve + combine ----------
// 128 blocks x 256 thr: block = (bh = idx&31, q = idx>>5) handling rows
// q*256..q*256+255. kb = f(-s_i) directly (no search); fwd table read at q0,
// bwd at q1; boundary bucket [q0,q1) resolved with exact d_j < thr compares.
__global__ __launch_bounds__(256) void out_kernel(
    const float* __restrict__ h_ws, const float* __restrict__ sarr,
    const float* __restrict__ dsrt_g, const int* __restrict__ pj_g,
    const int* __restrict__ bs_g, const float* __restrict__ prm_g,
    const float* __restrict__ sPB_g, const float* __restrict__ sSF_g,
    const float* __restrict__ ctF_g, const float* __restrict__ ctB_g,
    const float* __restrict__ ctSF_g, const float* __restrict__ ctSB_g,
    const float* __restrict__ tbl_g, float* __restrict__ out)
{
    __shared__ float dsS[CN];              // bucket-ordered d
    __shared__ int   pjS[CN];              // bucket-ordered permutation
    __shared__ int   bsS[NBK + 1];         // bucket starts
    __shared__ float ctF[32 * 32], ctB[32 * 32];
    __shared__ float ctSF[32], ctSB[32];
    __shared__ float ofF[33 * 32], ofB[33 * 32];
    __shared__ float ofSF[33], ofSB[33];

    const int bh = blockIdx.x & 31, q = blockIdx.x >> 5;
    const int tid = threadIdx.x;

    #pragma unroll
    for (int rr = 0; rr < 4; ++rr) {
        const int idx = rr * 256 + tid;
        dsS[idx] = dsrt_g[bh * CN + idx];
        pjS[idx] = pj_g[bh * CN + idx];
        bsS[idx] = bs_g[bh * (NBK + 1) + idx];
        ctF[idx] = ctF_g[bh * 1024 + idx];
        ctB[idx] = ctB_g[bh * 1024 + idx];
    }
    if (tid == 0) bsS[NBK] = bs_g[bh * (NBK + 1) + NBK];
    if (tid < 32)       ctSF[tid] = ctSF_g[bh * 32 + tid];
    else if (tid < 64)  ctSB[tid - 32] = ctSB_g[bh * 32 + (tid - 32)];
    __syncthreads();

    if (tid < 32) {                  // fwd vector chunk offsets, dd = tid
        float run = 0.f;
        for (int c = 0; c < 32; ++c) { ofF[c * 32 + tid] = run; run += ctF[c * 32 + tid]; }
        ofF[32 * 32 + tid] = run;
    } else if (tid < 64) {           // bwd vector chunk offsets
        const int dd = tid - 32;
        float run = 0.f;
        ofB[32 * 32 + dd] = 0.f;
        for (int c = 31; c >= 0; --c) { ofB[c * 32 + dd] = run; run += ctB[c * 32 + dd]; }
    } else if (tid == 64) {          // fwd scalar chunk offsets
        float run = 0.f;
        for (int c = 0; c < 32; ++c) { ofSF[c] = run; run += ctSF[c]; }
        ofSF[32] = run;
    } else if (tid == 65) {          // bwd scalar chunk offsets
        float run = 0.f;
        ofSB[32] = 0.f;
        for (int c = 31; c >= 0; --c) { ofSB[c] = run; run += ctSB[c]; }
    }
    __syncthreads();

    const int i = q * 256 + tid;
    const float s = sarr[bh * CN + i];
    const float c1 = __expf(s), c2v = __expf(0.2f * s), thr = -s;
    const float mnb = prm_g[bh * 2], invw = prm_g[bh * 2 + 1];
    const int kb = (int)fminf(fmaxf((thr - mnb) * invw, 0.0f), 1023.0f);  // same f as count
    const int q0 = bsS[kb], q1 = bsS[kb + 1];
    const int kcf = q0 >> 5, kcb = q1 >> 5;

    float pbs = sPB_g[bh * TROWS + q0] + ofSF[kcf];
    float sfs = sSF_g[bh * TROWS + q1] + ofSB[kcb];

    const float4* trf = (const float4*)(tbl_g + (size_t)bh * TROWS * 64 + (size_t)q0 * 64);
    const float4* trb = (const float4*)(tbl_g + (size_t)bh * TROWS * 64 + (size_t)q1 * 64 + 32);
    float4 vF[8], vB[8];
    #pragma unroll
    for (int qq = 0; qq < 8; ++qq) {
        const float4 pb = trf[qq], oa = *(const float4*)(&ofF[kcf * 32 + qq * 4]);
        const float4 sf = trb[qq], ob = *(const float4*)(&ofB[kcb * 32 + qq * 4]);
        vF[qq] = make_float4(pb.x + oa.x, pb.y + oa.y, pb.z + oa.z, pb.w + oa.w);
        vB[qq] = make_float4(sf.x + ob.x, sf.y + ob.y, sf.z + ob.z, sf.w + ob.w);
    }

    // exact resolve of the boundary bucket (avg ~2.6 elems)
    const float* hb = h_ws + (size_t)bh * CN * CHD;
    for (int p = q0; p < q1; ++p) {
        const float dq = dsS[p];
        const float4* hr = (const float4*)(hb + (size_t)pjS[p] * CHD);
        const bool pre = (dq < thr);
        const float w = __expf(pre ? 0.2f * dq : dq);
        if (pre) pbs += w; else sfs += w;
        #pragma unroll
        for (int qq = 0; qq < 8; ++qq) {
            const float4 hv = hr[qq];
            if (pre) {
                vF[qq].x += w * hv.x; vF[qq].y += w * hv.y;
                vF[qq].z += w * hv.z; vF[qq].w += w * hv.w;
            } else {
                vB[qq].x += w * hv.x; vB[qq].y += w * hv.y;
                vB[qq].z += w * hv.z; vB[qq].w += w * hv.w;
            }
        }
    }

    const float inv = 1.0f / (c2v * pbs + c1 * sfs);
    const int b = bh >> 2, hh = bh & 3;
    float4* o = (float4*)(out + (size_t)(b * CN + i) * CF + hh * 32);
    #pragma unroll
    for (int qq = 0; qq < 8; ++qq) {
        o[qq] = make_float4((c2v * vF[qq].x + c1 * vB[qq].x) * inv,
                            (c2v * vF[qq].y + c1 * vB[qq].y) * inv,
                            (c2v * vF[qq].z + c1 * vB[qq].z) * inv,
                            (c2v * vF[qq].w + c1 * vB[qq].w) * inv);
    }
}

extern "C" void kernel_launch(void* const* d_in, const int* in_sizes, int n_in,
                              void* d_out, int out_size, void* d_ws, size_t ws_size,
                              hipStream_t stream) {
    const float* x     = (const float*)d_in[0];
    const float* W     = (const float*)d_in[1];
    const float* a_src = (const float*)d_in[2];
    const float* a_dst = (const float*)d_in[3];
    float* out = (float*)d_out;

    char* ws = (char*)d_ws;
    size_t off = 0;
    float* h_ws = (float*)(ws + off); off += (size_t)CROWS * CF * 4;          // 4 MB
    float* sarr = (float*)(ws + off); off += (size_t)CBH * CN * 4;            // 128 KB
    float* darr = (float*)(ws + off); off += (size_t)CBH * CN * 4;            // 128 KB
    float* tblg = (float*)(ws + off); off += (size_t)CBH * TROWS * 64 * 4;    // 8.4 MB
    float* dsrt = (float*)(ws + off); off += (size_t)CBH * CN * 4;            // 128 KB
    int*   pjg  = (int*)  (ws + off); off += (size_t)CBH * CN * 4;            // 128 KB
    float* sPBg = (float*)(ws + off); off += (size_t)CBH * TROWS * 4;         // 131 KB
    float* sSFg = (float*)(ws + off); off += (size_t)CBH * TROWS * 4;         // 131 KB
    float* ctFg = (float*)(ws + off); off += (size_t)CBH * 32 * 32 * 4;       // 128 KB
    float* ctBg = (float*)(ws + off); off += (size_t)CBH * 32 * 32 * 4;       // 128 KB
    float* ctSFg= (float*)(ws + off); off += (size_t)CBH * 32 * 4;            // 4 KB
    float* ctSBg= (float*)(ws + off); off += (size_t)CBH * 32 * 4;            // 4 KB
    int*   bsg  = (int*)  (ws + off); off += (size_t)CBH * (NBK + 1) * 4;     // 131 KB
    float* prmg = (float*)(ws + off); off += (size_t)CBH * 2 * 4;             // 256 B
    (void)ws_size;

    proj_kernel<<<CROWS / 8, 256, 0, stream>>>(x, W, a_src, a_dst, h_ws, sarr, darr);
    count_kernel<<<CBH, 1024, 0, stream>>>(darr, dsrt, pjg, bsg, prmg, sPBg, sSFg, tblg);
    scan_kernel<<<256, 256, 0, stream>>>(h_ws, dsrt, pjg, tblg, sPBg, sSFg,
                                         ctFg, ctBg, ctSFg, ctSBg);
    out_kernel<<<128, 256, 0, stream>>>(h_ws, sarr, dsrt, pjg, bsg, prmg,
                                        sPBg, sSFg, ctFg, ctBg, ctSFg, ctSBg, tblg, out);
}